// Round 7
// baseline (91.977 us; speedup 1.0000x reference)
//
#include <hip/hip_runtime.h>
#include <math.h>

#define NQ 12
#define TPB 512

// One 512-thread block (8 waves) per sample; 4096-amp state split 8-way:
// each thread holds v[8] float2 = 16 VGPRs of state.
//
// R4/R5/R6 lesson: with >=256-thread workgroups this toolchain's allocator
// pins a 64-VGPR budget (8 waves/EU) regardless of __launch_bounds__ 2nd arg
// or amdgpu_waves_per_eu(4,4), and spills anything bigger (VGPR_Count=64 +
// ~38MB scratch writes in all three rounds). So: DESIGN for 64 VGPRs --
// 16-reg state + ~30 temps fits, and 8 waves/EU becomes a feature
// (1024 blocks = 4 blocks/CU x 8 waves = 32 waves/CU latency hiding).
//
// Amp index j (12 bits), qubit q <-> j bit 11-q. Four register layouts
// (t = thread 0..511 supplies 9 bits, r = reg index 3 bits):
//   A: j = (r<<9)|t                 r = j[11:9] = qubits 0..2
//   B: j = (t[8:6]<<9)|(r<<6)|t[5:0] r = j[8:6]  = qubits 3..5
//   C: j = (t[8:3]<<6)|(r<<3)|t[2:0] r = j[5:3]  = qubits 6..8
//   D: j = (t<<3)|r                 r = j[2:0]  = qubits 9..11
// In every phase, gate on qubit qb+d pairs over r-bit (2-d).
// LDS: amp j lives at phys(j) = (j&~15)|((j^(j>>4)^(j>>8))&15) (XOR swizzle;
// all transpose patterns <=2-way bank aliased -- free per m136).
//
// Circuit after algebraic reduction (verified R2-R5, absmax ~1e-3):
//   init = layer-0 RX product state with CNOT-ring FOLDED via inverse perm,
//   12 fused phase-reduced RZ*RY, 12 RX, ring scatter, 12 RY (final RZ
//   dropped -- phase-only), Z-expectations.
// The 60 uniform sincos pairs are precomputed once into LDS co[].

__device__ __forceinline__ int phys(int j) {
    return (j & ~15) | ((j ^ (j >> 4) ^ (j >> 8)) & 15);
}

__device__ __forceinline__ void g_fused(float2& a0, float2& a1,
                                        float cy, float sy, float cz, float sz)
{
    // RZ*RY with global phase stripped: n0 = cy a0 - sy a1 (real row),
    // n1 = e^{i*thz} (sy a0 + cy a1)
    float n0x = cy*a0.x - sy*a1.x;
    float n0y = cy*a0.y - sy*a1.y;
    float wx  = sy*a0.x + cy*a1.x;
    float wy  = sy*a0.y + cy*a1.y;
    a0.x = n0x; a0.y = n0y;
    a1.x = cz*wx - sz*wy;
    a1.y = cz*wy + sz*wx;
}

__device__ __forceinline__ void g_rx(float2& a0, float2& a1, float c, float s)
{
    float n0x = c*a0.x + s*a1.y;
    float n0y = c*a0.y - s*a1.x;
    float n1x = c*a1.x + s*a0.y;
    float n1y = c*a1.y - s*a0.x;
    a0.x = n0x; a0.y = n0y; a1.x = n1x; a1.y = n1y;
}

__device__ __forceinline__ void g_ry(float2& a0, float2& a1, float c, float s)
{
    float n0x = c*a0.x - s*a1.x;
    float n0y = c*a0.y - s*a1.y;
    float n1x = s*a0.x + c*a1.x;
    float n1y = s*a0.y + c*a1.y;
    a0.x = n0x; a0.y = n0y; a1.x = n1x; a1.y = n1y;
}

#define FOR_PAIRS3(RB, STMT) do {                                     \
    const int msk_ = 1 << (RB);                                       \
    _Pragma("unroll")                                                 \
    for (int h_ = 0; h_ < 4; ++h_) {                                  \
        const int i0 = ((h_ & ~(msk_ - 1)) << 1) | (h_ & (msk_ - 1)); \
        const int i1 = i0 | msk_;                                     \
        STMT;                                                         \
    } } while (0)

// layout element indices (t in scope)
#define J_A(r) (((r) << 9) | t)
#define J_B(r) (((t >> 6) << 9) | ((r) << 6) | (t & 63))
#define J_C(r) (((t >> 3) << 6) | ((r) << 3) | (t & 7))
#define J_D(r) ((t << 3) | (r))

#define XPOSE(JSRC, JDST) do {                                        \
    _Pragma("unroll")                                                 \
    for (int r_ = 0; r_ < 8; ++r_) S[phys(JSRC(r_))] = v[r_];         \
    __syncthreads();                                                  \
    _Pragma("unroll")                                                 \
    for (int r_ = 0; r_ < 8; ++r_) v[r_] = S[phys(JDST(r_))];         \
    __syncthreads();                                                  \
  } while (0)

// co[] table (float2 = (cos, sin)):
//  [0..11] L0 RX half-angles   [12..23] L1 RX half-angles
//  [24..35] L0 RY half-angles  [36..47] L0 RZ FULL angles
//  [48..59] L1 RY half-angles
#define G_PHASE(QB) do { _Pragma("unroll")                                  \
    for (int d_ = 0; d_ < 3; ++d_) {                                        \
        float2 csy = co[24 + (QB) + d_];                                    \
        float2 csz = co[36 + (QB) + d_];                                    \
        FOR_PAIRS3(2 - d_, g_fused(v[i0], v[i1], csy.x, csy.y,              \
                                   csz.x, csz.y));                          \
    } } while (0)

#define RX_PHASE(QB) do { _Pragma("unroll")                                 \
    for (int d_ = 0; d_ < 3; ++d_) {                                        \
        float2 cs = co[12 + (QB) + d_];                                     \
        FOR_PAIRS3(2 - d_, g_rx(v[i0], v[i1], cs.x, cs.y));                 \
    } } while (0)

#define RY_PHASE(QB) do { _Pragma("unroll")                                 \
    for (int d_ = 0; d_ < 3; ++d_) {                                        \
        float2 cs = co[48 + (QB) + d_];                                     \
        FOR_PAIRS3(2 - d_, g_ry(v[i0], v[i1], cs.x, cs.y));                 \
    } } while (0)

__global__ __launch_bounds__(TPB) void vqc_kernel(
    const float* __restrict__ x,    // [B, 12]
    const float* __restrict__ th,   // [2, 12, 2]
    const float* __restrict__ lm,   // [2, 12]
    float* __restrict__ out)        // [B, 12]
{
    __shared__ float2 S[4096];
    __shared__ float2 co[60];

    const int b = blockIdx.x;
    const int t = threadIdx.x;
    const int l = t & 63;
    const int w = t >> 6;

    // ---- cooperative coefficient precompute (60 sincos per block) ----
    if (t < 60) {
        float h;
        if (t < 12)       h = 0.5f * lm[t] * x[b * NQ + t];
        else if (t < 24)  h = 0.5f * lm[t] * x[b * NQ + (t - 12)];
        else if (t < 36)  h = 0.5f * th[2 * (t - 24)];
        else if (t < 48)  h = th[2 * (t - 36) + 1];
        else              h = 0.5f * th[24 + 2 * (t - 48)];
        float c, s;
        __sincosf(h, &s, &c);
        co[t].x = c; co[t].y = s;
    }
    __syncthreads();

    float2 v[8];

    // ---- init in layout A with layer-0 ring folded (inverse perm) ----
    // i = P^{-1}(j): i_p = j_p^j_{p+1} (p<=9), i_10 = j_10^j_0^j_11,
    // i_11 = j_0^j_11. With j = (r<<9)|t:
    //   i[0..7] = t^(t>>1)  (qubits 11..4)
    //   i8 = t8^r0 (qubit 3); i9 = r0^r1 (qubit 2);
    //   i10 = t0^r1^r2 (qubit 1); i11 = t0^r2 (qubit 0)
    {
        const int g = (t ^ (t >> 1)) & 0xFF;
        float Pt = 1.0f;
#pragma unroll
        for (int p = 0; p < 8; ++p) {
            float2 cs = co[11 - p];                 // qubit 11-p (broadcast)
            Pt *= ((g >> p) & 1) ? cs.y : cs.x;
        }
        const int ct = __popc(g);
        const int t8 = (t >> 8) & 1, t0 = t & 1;
        float2 q3 = co[3], q2 = co[2], q1 = co[1], q0 = co[0];
        const float u3  = t8 ? q3.y : q3.x;   // qubit 3, r0=0
        const float u3n = t8 ? q3.x : q3.y;   //          r0=1
        const float u1  = t0 ? q1.y : q1.x;   // qubit 1, (r1^r2)=0
        const float u1n = t0 ? q1.x : q1.y;
        const float u0  = t0 ? q0.y : q0.x;   // qubit 0, r2=0
        const float u0n = t0 ? q0.x : q0.y;
#pragma unroll
        for (int r = 0; r < 8; ++r) {
            const int r0 = r & 1, r1 = (r >> 1) & 1, r2 = (r >> 2) & 1;
            const int i9 = r0 ^ r1;
            float m = Pt * (r0 ? u3n : u3) * (i9 ? q2.y : q2.x)
                         * ((r1 ^ r2) ? u1n : u1) * (r2 ? u0n : u0);
            int k = (ct + (t8 ^ r0) + i9 + (t0 ^ r1 ^ r2) + (t0 ^ r2)) & 3;
            v[r].x = (k == 0) ? m : ((k == 2) ? -m : 0.0f);
            v[r].y = (k == 3) ? m : ((k == 1) ? -m : 0.0f);
        }
    }

    // ---- layer-0 fused RZ*RY, 4 phases ----
    G_PHASE(0);                       // qubits 0..2  in A
    XPOSE(J_A, J_B);
    G_PHASE(3);                       // qubits 3..5  in B
    XPOSE(J_B, J_C);
    G_PHASE(6);                       // qubits 6..8  in C
    XPOSE(J_C, J_D);
    G_PHASE(9);                       // qubits 9..11 in D

    // ---- layer-1 RX, walking back D -> A ----
    RX_PHASE(9);                      // in D
    XPOSE(J_D, J_C);
    RX_PHASE(6);                      // in C
    XPOSE(J_C, J_B);
    RX_PHASE(3);                      // in B
    XPOSE(J_B, J_A);
    RX_PHASE(0);                      // in A

    // ---- layer-1 CNOT ring: scatter perm(j), land in layout D ----
#pragma unroll
    for (int r = 0; r < 8; ++r) {
        int j = J_A(r);
        int y = j ^ (j >> 1); y ^= y >> 2; y ^= y >> 4; y ^= y >> 8;
        int p = (y & 0x7FF) | (((__popc(j) ^ (j >> 11)) & 1) << 11);
        S[phys(p)] = v[r];
    }
    __syncthreads();
#pragma unroll
    for (int r = 0; r < 8; ++r) v[r] = S[phys(J_D(r))];
    __syncthreads();

    // ---- layer-1 RY (final RZ dropped: phase-only), D -> A ----
    RY_PHASE(9);                      // in D
    XPOSE(J_D, J_C);
    RY_PHASE(6);                      // in C
    XPOSE(J_C, J_B);
    RY_PHASE(3);                      // in B
    XPOSE(J_B, J_A);
    RY_PHASE(0);                      // in A

    // ---- measurement in A: qubits 0..2 from r bits, 3..11 from t bits ----
    float ptot = 0.0f;
    float zb[3] = {0.f, 0.f, 0.f};
#pragma unroll
    for (int r = 0; r < 8; ++r) {
        float p = v[r].x * v[r].x + v[r].y * v[r].y;
        ptot += p;
#pragma unroll
        for (int q = 0; q < 3; ++q)
            zb[q] += ((r >> (2 - q)) & 1) ? -p : p;   // compile-time signs
    }
    float tv[NQ];
#pragma unroll
    for (int q = 0; q < 3; ++q) tv[q] = zb[q];
#pragma unroll
    for (int q = 3; q < 12; ++q)
        tv[q] = ((t >> (11 - q)) & 1) ? -ptot : ptot;

#pragma unroll
    for (int q = 0; q < NQ; ++q) {
#pragma unroll
        for (int m = 1; m < 64; m <<= 1)
            tv[q] += __shfl_xor(tv[q], m, 64);
    }

    float* red = (float*)S;   // S dead (barrier at end of last XPOSE)
    if (l == 0) {
#pragma unroll
        for (int q = 0; q < NQ; ++q) red[w * NQ + q] = tv[q];
    }
    __syncthreads();
    if (t < NQ) {
        float r = 0.f;
#pragma unroll
        for (int ww = 0; ww < 8; ++ww) r += red[ww * NQ + t];
        out[b * NQ + t] = r;
    }
}

extern "C" void kernel_launch(void* const* d_in, const int* in_sizes, int n_in,
                              void* d_out, int out_size, void* d_ws, size_t ws_size,
                              hipStream_t stream) {
    const int B = in_sizes[0] / NQ;  // 1024
    vqc_kernel<<<B, TPB, 0, stream>>>((const float*)d_in[0],
                                      (const float*)d_in[1],
                                      (const float*)d_in[2],
                                      (float*)d_out);
}

// Round 8
// 87.060 us; speedup vs baseline: 1.0565x; 1.0565x over previous
//
#include <hip/hip_runtime.h>
#include <math.h>

#define NQ 12
#define TPB 512

// One 512-thread block (8 waves) per sample; 4096-amp state split 8-way:
// v[8] float2 per thread (16 VGPRs of state -- fits the 64-VGPR budget the
// allocator pins for big workgroups; R7 verified no spill at VGPR=52).
//
// Amp index j (12 bits), qubit q <-> j bit 11-q. Register layouts
// (t = thread 0..511 gives 9 bits, r = reg index 3 bits):
//   A: j = (r<<9)|t                  r = j[11:9] = qubits 0..2
//   B: j = (t[8:6]<<9)|(r<<6)|t[5:0] r = j[8:6]  = qubits 3..5
//   C: j = (t[8:3]<<6)|(r<<3)|t[2:0] r = j[5:3]  = qubits 6..8
//   D: j = (t<<3)|r                  r = j[2:0]  = qubits 9..11
// KEY: B/C/D all have wave bits = j[11:9], and the global swizzle
// sg(j) = (j&~15)|((j^(j>>4)^(j>>8))&15) keeps each 512-amp slice
// contiguous -> B<->C and C<->D roundtrips are WAVE-LOCAL: no
// __syncthreads needed (same-wave LDS ops are ordered). Only A-side
// roundtrips (A->B, B->A x2, ring) use barriers: 8 total vs R7's 21.
//
// VALU: gates use v_pk_fma_f32/v_pk_mul_f32 (CDNA dual-FP32). RY / fused
// RZ*RY row-0 pack directly ((re,im) share real coeffs). For layer-1 RX we
// switch basis a_j = i^popc(j) b_j, making RX the REAL rotation
// [[c,s],[-s,c]] (pk-friendly, no component swaps); diagonal quarter-turn
// transforms are applied entering/leaving the RX block.
//
// Circuit (algebra verified R2-R7, absmax ~1e-3): init = L0 RX product
// state with CNOT ring folded (inverse perm); 12 fused phase-stripped
// RZ*RY; 12 RX (b-basis); ring scatter; 12 RY (final RZ dropped); <Z_q>.

__device__ __forceinline__ int sg(int j) {
    return (j & ~15) | ((j ^ (j >> 4) ^ (j >> 8)) & 15);
}

__device__ __forceinline__ float2 pk_mul(float2 a, float2 b) {
    float2 d;
    asm("v_pk_mul_f32 %0, %1, %2" : "=v"(d) : "v"(a), "v"(b));
    return d;
}
__device__ __forceinline__ float2 pk_fma(float2 a, float2 b, float2 c) {
    float2 d;
    asm("v_pk_fma_f32 %0, %1, %2, %3" : "=v"(d) : "v"(a), "v"(b), "v"(c));
    return d;
}

#define FOR_PAIRS3(RB, STMT) do {                                     \
    const int msk_ = 1 << (RB);                                       \
    _Pragma("unroll")                                                 \
    for (int h_ = 0; h_ < 4; ++h_) {                                  \
        const int i0 = ((h_ & ~(msk_ - 1)) << 1) | (h_ & (msk_ - 1)); \
        const int i1 = i0 | msk_;                                     \
        STMT;                                                         \
    } } while (0)

// layout element indices (t in scope)
#define J_A(r) (((r) << 9) | t)
#define J_B(r) (((t >> 6) << 9) | ((r) << 6) | (t & 63))
#define J_C(r) (((t >> 3) << 6) | ((r) << 3) | (t & 7))
#define J_D(r) ((t << 3) | (r))

// wave-local roundtrip: same-wave LDS ordering, no barrier
#define LOCAL_X(JS, JD) do {                                          \
    _Pragma("unroll")                                                 \
    for (int r_ = 0; r_ < 8; ++r_) S[sg(JS(r_))] = v[r_];             \
    _Pragma("unroll")                                                 \
    for (int r_ = 0; r_ < 8; ++r_) v[r_] = S[sg(JD(r_))];             \
  } while (0)

// cross-wave roundtrip: one barrier between write and read
#define CROSS_X(JS, JD) do {                                          \
    _Pragma("unroll")                                                 \
    for (int r_ = 0; r_ < 8; ++r_) S[sg(JS(r_))] = v[r_];             \
    __syncthreads();                                                  \
    _Pragma("unroll")                                                 \
    for (int r_ = 0; r_ < 8; ++r_) v[r_] = S[sg(JD(r_))];             \
  } while (0)

// co[] table (float2 = (cos,sin)):
//  [0..11] L0 RX half-angles   [12..23] L1 RX half-angles
//  [24..35] L0 RY half-angles  [36..47] L0 RZ FULL angles
//  [48..59] L1 RY half-angles

// fused phase-stripped RZ*RY: n0 = cy a0 - sy a1 ; a1 = e^{i thz}(sy a0 + cy a1)
#define G_GATE(q, RB) do {                                                  \
        float2 csy = co[24 + (q)], csz = co[36 + (q)];                      \
        float2 cy2  = make_float2(csy.x, csy.x);                            \
        float2 sy2  = make_float2(csy.y, csy.y);                            \
        float2 msy2 = make_float2(-csy.y, -csy.y);                          \
        FOR_PAIRS3(RB, {                                                    \
            float2 n0 = pk_fma(v[i1], msy2, pk_mul(v[i0], cy2));            \
            float2 wv = pk_fma(v[i0], sy2, pk_mul(v[i1], cy2));             \
            v[i0] = n0;                                                     \
            v[i1].x = csz.x * wv.x - csz.y * wv.y;                          \
            v[i1].y = csz.x * wv.y + csz.y * wv.x;                          \
        });                                                                 \
    } while (0)

// layer-1 RX in b-basis: real rotation n0 = c a0 + s a1 ; n1 = -s a0 + c a1
#define RXB_GATE(q, RB) do {                                                \
        float2 cs = co[12 + (q)];                                           \
        float2 c2  = make_float2(cs.x, cs.x);                               \
        float2 s2  = make_float2(cs.y, cs.y);                               \
        float2 ms2 = make_float2(-cs.y, -cs.y);                             \
        FOR_PAIRS3(RB, {                                                    \
            float2 n0 = pk_fma(v[i1], s2, pk_mul(v[i0], c2));               \
            float2 n1 = pk_fma(v[i0], ms2, pk_mul(v[i1], c2));              \
            v[i0] = n0; v[i1] = n1;                                         \
        });                                                                 \
    } while (0)

// RY: n0 = c a0 - s a1 ; n1 = s a0 + c a1
#define RY_GATE(q, RB) do {                                                 \
        float2 cs = co[48 + (q)];                                           \
        float2 c2  = make_float2(cs.x, cs.x);                               \
        float2 s2  = make_float2(cs.y, cs.y);                               \
        float2 ms2 = make_float2(-cs.y, -cs.y);                             \
        FOR_PAIRS3(RB, {                                                    \
            float2 n0 = pk_fma(v[i1], ms2, pk_mul(v[i0], c2));              \
            float2 n1 = pk_fma(v[i0], s2, pk_mul(v[i1], c2));               \
            v[i0] = n0; v[i1] = n1;                                         \
        });                                                                 \
    } while (0)

#define G_PHASE(QB)  do { _Pragma("unroll")                                 \
    for (int d_ = 0; d_ < 3; ++d_) G_GATE((QB) + d_, 2 - d_); } while (0)
#define RXB_PHASE(QB) do { _Pragma("unroll")                                \
    for (int d_ = 0; d_ < 3; ++d_) RXB_GATE((QB) + d_, 2 - d_); } while (0)
#define RY_PHASE(QB) do { _Pragma("unroll")                                 \
    for (int d_ = 0; d_ < 3; ++d_) RY_GATE((QB) + d_, 2 - d_); } while (0)

__global__ __launch_bounds__(TPB) void vqc_kernel(
    const float* __restrict__ x,    // [B, 12]
    const float* __restrict__ th,   // [2, 12, 2]
    const float* __restrict__ lm,   // [2, 12]
    float* __restrict__ out)        // [B, 12]
{
    __shared__ float2 S[4096];
    __shared__ float2 co[60];

    const int b = blockIdx.x;
    const int t = threadIdx.x;
    const int l = t & 63;
    const int w = t >> 6;

    // ---- cooperative coefficient precompute (60 sincos per block) ----
    if (t < 60) {
        float h;
        if (t < 12)       h = 0.5f * lm[t] * x[b * NQ + t];
        else if (t < 24)  h = 0.5f * lm[t] * x[b * NQ + (t - 12)];
        else if (t < 36)  h = 0.5f * th[2 * (t - 24)];
        else if (t < 48)  h = th[2 * (t - 36) + 1];
        else              h = 0.5f * th[24 + 2 * (t - 48)];
        float c, s;
        __sincosf(h, &s, &c);
        co[t].x = c; co[t].y = s;
    }
    __syncthreads();                                   // barrier 1

    float2 v[8];

    // ---- init in layout A with layer-0 ring folded (inverse perm) ----
    // (verified R7) i[0..7] = (t^(t>>1)) qubits 11..4; i8 = t8^r0 (q3);
    // i9 = r0^r1 (q2); i10 = t0^r1^r2 (q1); i11 = t0^r2 (q0)
    {
        const int g = (t ^ (t >> 1)) & 0xFF;
        float Pt = 1.0f;
#pragma unroll
        for (int p = 0; p < 8; ++p) {
            float2 cs = co[11 - p];
            Pt *= ((g >> p) & 1) ? cs.y : cs.x;
        }
        const int ct = __popc(g);
        const int t8 = (t >> 8) & 1, t0 = t & 1;
        float2 q3 = co[3], q2 = co[2], q1 = co[1], q0 = co[0];
        const float u3  = t8 ? q3.y : q3.x;
        const float u3n = t8 ? q3.x : q3.y;
        const float u1  = t0 ? q1.y : q1.x;
        const float u1n = t0 ? q1.x : q1.y;
        const float u0  = t0 ? q0.y : q0.x;
        const float u0n = t0 ? q0.x : q0.y;
#pragma unroll
        for (int r = 0; r < 8; ++r) {
            const int r0 = r & 1, r1 = (r >> 1) & 1, r2 = (r >> 2) & 1;
            const int i9 = r0 ^ r1;
            float m = Pt * (r0 ? u3n : u3) * (i9 ? q2.y : q2.x)
                         * ((r1 ^ r2) ? u1n : u1) * (r2 ? u0n : u0);
            int k = (ct + (t8 ^ r0) + i9 + (t0 ^ r1 ^ r2) + (t0 ^ r2)) & 3;
            v[r].x = (k == 0) ? m : ((k == 2) ? -m : 0.0f);
            v[r].y = (k == 3) ? m : ((k == 1) ? -m : 0.0f);
        }
    }

    // ---- layer-0 fused RZ*RY ----
    G_PHASE(0);                       // qubits 0..2  in A
    CROSS_X(J_A, J_B);                // barrier 2
    G_PHASE(3);                       // qubits 3..5  in B
    LOCAL_X(J_B, J_C);                // wave-local, no barrier
    G_PHASE(6);                       // qubits 6..8  in C
    LOCAL_X(J_C, J_D);
    G_PHASE(9);                       // qubits 9..11 in D

    // ---- enter b-basis: b_j = (-i)^popc(j) a_j  (layout D: j = t<<3|r) ----
    {
        const int pct = __popc(t);
#pragma unroll
        for (int r = 0; r < 8; ++r) {
            int k = (pct + __popc(r)) & 3;
            float2 a = v[r];
            float nx = (k & 1) ? a.y : a.x;
            float ny = (k & 1) ? -a.x : a.y;
            v[r].x = (k & 2) ? -nx : nx;
            v[r].y = (k & 2) ? -ny : ny;
        }
    }

    // ---- layer-1 RX (b-basis real rotations), D -> A ----
    RXB_PHASE(9);                     // in D
    LOCAL_X(J_D, J_C);
    RXB_PHASE(6);                     // in C
    LOCAL_X(J_C, J_B);
    RXB_PHASE(3);                     // in B
    CROSS_X(J_B, J_A);                // barrier 3
    RXB_PHASE(0);                     // in A

    // ---- leave b-basis: a_j = i^popc(j) b_j  (layout A: j = r<<9|t) ----
    {
        const int pct = __popc(t);
#pragma unroll
        for (int r = 0; r < 8; ++r) {
            int k = (pct + __popc(r)) & 3;
            float2 a = v[r];
            float nx = (k & 1) ? -a.y : a.x;
            float ny = (k & 1) ? a.x : a.y;
            v[r].x = (k & 2) ? -nx : nx;
            v[r].y = (k & 2) ? -ny : ny;
        }
    }

    // ---- layer-1 CNOT ring: scatter perm(j), land in layout D ----
    __syncthreads();                  // barrier 4: all A-reads done before scatter
#pragma unroll
    for (int r = 0; r < 8; ++r) {
        int j = J_A(r);
        int y = j ^ (j >> 1); y ^= y >> 2; y ^= y >> 4; y ^= y >> 8;
        int p = (y & 0x7FF) | (((__popc(j) ^ (j >> 11)) & 1) << 11);
        S[sg(p)] = v[r];
    }
    __syncthreads();                  // barrier 5
#pragma unroll
    for (int r = 0; r < 8; ++r) v[r] = S[sg(J_D(r))];

    // ---- layer-1 RY (final RZ dropped: phase-only), D -> A ----
    RY_PHASE(9);                      // in D
    LOCAL_X(J_D, J_C);
    RY_PHASE(6);                      // in C
    LOCAL_X(J_C, J_B);
    RY_PHASE(3);                      // in B
    CROSS_X(J_B, J_A);                // barrier 6
    RY_PHASE(0);                      // in A

    // ---- measurement in A: qubits 0..2 from r bits, 3..11 from t bits ----
    float ptot = 0.0f;
    float zb[3] = {0.f, 0.f, 0.f};
#pragma unroll
    for (int r = 0; r < 8; ++r) {
        float p = v[r].x * v[r].x + v[r].y * v[r].y;
        ptot += p;
#pragma unroll
        for (int q = 0; q < 3; ++q)
            zb[q] += ((r >> (2 - q)) & 1) ? -p : p;
    }
    float tv[NQ];
#pragma unroll
    for (int q = 0; q < 3; ++q) tv[q] = zb[q];
#pragma unroll
    for (int q = 3; q < 12; ++q)
        tv[q] = ((t >> (11 - q)) & 1) ? -ptot : ptot;

#pragma unroll
    for (int q = 0; q < NQ; ++q) {
#pragma unroll
        for (int m = 1; m < 64; m <<= 1)
            tv[q] += __shfl_xor(tv[q], m, 64);
    }

    __syncthreads();                  // barrier 7: all S reads done before red
    float* red = (float*)S;
    if (l == 0) {
#pragma unroll
        for (int q = 0; q < NQ; ++q) red[w * NQ + q] = tv[q];
    }
    __syncthreads();                  // barrier 8
    if (t < NQ) {
        float r = 0.f;
#pragma unroll
        for (int ww = 0; ww < 8; ++ww) r += red[ww * NQ + t];
        out[b * NQ + t] = r;
    }
}

extern "C" void kernel_launch(void* const* d_in, const int* in_sizes, int n_in,
                              void* d_out, int out_size, void* d_ws, size_t ws_size,
                              hipStream_t stream) {
    const int B = in_sizes[0] / NQ;  // 1024
    vqc_kernel<<<B, TPB, 0, stream>>>((const float*)d_in[0],
                                      (const float*)d_in[1],
                                      (const float*)d_in[2],
                                      (float*)d_out);
}

// Round 9
// 79.762 us; speedup vs baseline: 1.1531x; 1.0915x over previous
//
#include <hip/hip_runtime.h>
#include <math.h>

#define NQ 12
#define TPB 512

// One 512-thread block (8 waves) per sample; 4096-amp state split 8-way:
// v[8] float2/thread (16 VGPRs state; 64-VGPR budget, no spill since R7).
//
// Amp index j (12 bits), qubit q <-> j bit 11-q. Register layouts
// (t = thread gives 9 bits, r = reg index 3 bits):
//   A: j = (r<<9)|t                  r = j[11:9] = qubits 0..2
//   B: j = (t[8:6]<<9)|(r<<6)|t[5:0] r = j[8:6]  = qubits 3..5
//   C: j = (t[8:3]<<6)|(r<<3)|t[2:0] r = j[5:3]  = qubits 6..8
//   D: j = (t<<3)|r                  r = j[2:0]  = qubits 9..11
// B/C/D keep wave bits = j[11:9] -> B<->C, C<->D roundtrips are wave-local
// (no barrier; same-wave LDS is ordered). A-side crossings + ring barrier.
// LDS swizzle sg(j) = (j&~15)|((j^(j>>4)^(j>>8))&15), patterns verified R8.
//
// R8 lesson: kernel is LDS-PIPE-bound (per-CU shared): 32 waves x ~230 DS
// instrs. This round cuts DS work algebraically:
//  * M_q = RX(L1) * RZ(L0) * RY(L0) fused into ONE SU(2) gate per qubit
//    (no entangler between them in the circuit!) applied in Euler form
//    diag(1,e^{i psi}) RY(th) diag(1,e^{i phi}) -> one pass instead of two,
//    roundtrips 10 -> 7, b-basis transforms deleted.
//  * Measurement: 6-stage Walsh-Hadamard butterfly gives ALL lane-bit
//    signed sums at once (lanes 1,2,4,8,16,32 + total at lane 0):
//    24 shuffles vs 72.
// Circuit: init(D) = L0 RX product state with ring0 folded (inverse perm);
// M-pass D->C->B->A; ring1 A->A; RY-pass (final RZ dropped) A->B->C->D;
// measure in D.

__device__ __forceinline__ int sg(int j) {
    return (j & ~15) | ((j ^ (j >> 4) ^ (j >> 8)) & 15);
}

__device__ __forceinline__ float2 pk_mul(float2 a, float2 b) {
    float2 d;
    asm("v_pk_mul_f32 %0, %1, %2" : "=v"(d) : "v"(a), "v"(b));
    return d;
}
__device__ __forceinline__ float2 pk_fma(float2 a, float2 b, float2 c) {
    float2 d;
    asm("v_pk_fma_f32 %0, %1, %2, %3" : "=v"(d) : "v"(a), "v"(b), "v"(c));
    return d;
}

#define FOR_PAIRS3(RB, STMT) do {                                     \
    const int msk_ = 1 << (RB);                                       \
    _Pragma("unroll")                                                 \
    for (int h_ = 0; h_ < 4; ++h_) {                                  \
        const int i0 = ((h_ & ~(msk_ - 1)) << 1) | (h_ & (msk_ - 1)); \
        const int i1 = i0 | msk_;                                     \
        STMT;                                                         \
    } } while (0)

#define J_A(r) (((r) << 9) | t)
#define J_B(r) (((t >> 6) << 9) | ((r) << 6) | (t & 63))
#define J_C(r) (((t >> 3) << 6) | ((r) << 3) | (t & 7))
#define J_D(r) ((t << 3) | (r))

// wave-local roundtrip (same-wave LDS ordering, no barrier)
#define LOCAL_X(JS, JD) do {                                          \
    _Pragma("unroll")                                                 \
    for (int r_ = 0; r_ < 8; ++r_) S[sg(JS(r_))] = v[r_];             \
    _Pragma("unroll")                                                 \
    for (int r_ = 0; r_ < 8; ++r_) v[r_] = S[sg(JD(r_))];             \
  } while (0)

// fused M_q = RX1*RZ0*RY0 as diag(1,e^{i psi}) RY(th) diag(1,e^{i phi}):
// mA[q] = (cth, sth, psi.x, psi.y) ; mB[q] = (phi.x, phi.y)
#define M_GATE(q, RB) do {                                                  \
        float4 A4 = mA[q]; float2 P2 = mB[q];                               \
        float2 c2  = make_float2(A4.x, A4.x);                               \
        float2 s2  = make_float2(A4.y, A4.y);                               \
        float2 ms2 = make_float2(-A4.y, -A4.y);                             \
        FOR_PAIRS3(RB, {                                                    \
            float2 a1 = v[i1];                                              \
            float2 b1 = make_float2(A4.z*a1.x - A4.w*a1.y,                  \
                                    A4.z*a1.y + A4.w*a1.x);                 \
            float2 n0 = pk_fma(b1, ms2, pk_mul(v[i0], c2));                 \
            float2 n1 = pk_fma(v[i0], s2, pk_mul(b1, c2));                  \
            v[i0] = n0;                                                     \
            v[i1] = make_float2(P2.x*n1.x - P2.y*n1.y,                      \
                                P2.x*n1.y + P2.y*n1.x);                     \
        });                                                                 \
    } while (0)

#define RY_GATE(q, RB) do {                                                 \
        float2 cs = coY[q];                                                 \
        float2 c2  = make_float2(cs.x, cs.x);                               \
        float2 s2  = make_float2(cs.y, cs.y);                               \
        float2 ms2 = make_float2(-cs.y, -cs.y);                             \
        FOR_PAIRS3(RB, {                                                    \
            float2 n0 = pk_fma(v[i1], ms2, pk_mul(v[i0], c2));              \
            float2 n1 = pk_fma(v[i0], s2, pk_mul(v[i1], c2));               \
            v[i0] = n0; v[i1] = n1;                                         \
        });                                                                 \
    } while (0)

#define M_PHASE(QB)  do { _Pragma("unroll")                                 \
    for (int d_ = 0; d_ < 3; ++d_) M_GATE((QB) + d_, 2 - d_); } while (0)
#define RY_PHASE(QB) do { _Pragma("unroll")                                 \
    for (int d_ = 0; d_ < 3; ++d_) RY_GATE((QB) + d_, 2 - d_); } while (0)

__global__ __launch_bounds__(TPB) void vqc_kernel(
    const float* __restrict__ x,    // [B, 12]
    const float* __restrict__ th,   // [2, 12, 2]
    const float* __restrict__ lm,   // [2, 12]
    float* __restrict__ out)        // [B, 12]
{
    __shared__ float2 S[4096];
    __shared__ float4 mA[12];
    __shared__ float2 mB[12];
    __shared__ float2 coI[12];      // L0 RX half-angle (c,s)
    __shared__ float2 coY[12];      // L1 RY half-angle (c,s)
    __shared__ float red[8 * 12];

    const int b = blockIdx.x;
    const int t = threadIdx.x;
    const int l = t & 63;
    const int w = t >> 6;

    // ---- cooperative coefficient precompute ----
    if (t < 12) {
        float h = 0.5f * lm[t] * x[b * NQ + t];
        float c, s; __sincosf(h, &s, &c);
        coI[t] = make_float2(c, s);
    } else if (t < 24) {
        int q = t - 12;
        float h = 0.5f * th[24 + 2 * q];
        float c, s; __sincosf(h, &s, &c);
        coY[q] = make_float2(c, s);
    } else if (t < 36) {
        int q = t - 24;
        float ha = 0.5f * lm[12 + q] * x[b * NQ + q];  // L1 RX half
        float hy = 0.5f * th[2 * q];                   // L0 RY half
        float hz = 0.5f * th[2 * q + 1];               // L0 RZ half
        float ca, sa, cy, sy, cz, sz;
        __sincosf(ha, &sa, &ca);
        __sincosf(hy, &sy, &cy);
        __sincosf(hz, &sz, &cz);
        // M = RX(a) RZ(z) RY(y) in SU(2): alpha = M00, beta = M10
        float ax = ca*cy*cz + sa*sy*sz;
        float ay = -(ca*cy*sz + sa*sy*cz);
        float bx = ca*sy*cz - sa*cy*sz;
        float by = ca*sy*sz - sa*cy*cz;
        float na = ax*ax + ay*ay, nb = bx*bx + by*by;
        float ra = rsqrtf(fmaxf(na, 1e-30f));
        float rb = rsqrtf(fmaxf(nb, 1e-30f));
        float ux = ax*ra, uy = ay*ra;   // u = alpha/|alpha| = e^{-iP}
        float wx = bx*rb, wy = by*rb;   // w = beta /|beta|  = e^{+iD}
        // e^{i psi} = conj(u*w) ; e^{i phi} = conj(u)*w
        mA[q] = make_float4(na*ra, nb*rb,
                            ux*wx - uy*wy, -(ux*wy + uy*wx));
        mB[q] = make_float2(ux*wx + uy*wy, ux*wy - uy*wx);
    }
    __syncthreads();                                   // B1

    float2 v[8];

    // ---- init in layout D: L0 RX product state, ring0 folded ----
    // i = P^{-1}(j), j = (t<<3)|r:
    //  i0=r0^r1 (q11), i1=r1^r2 (q10), i2=r2^t0 (q9),
    //  i3..i9 = gray(t) bits 0..6 (qubits 8..2),
    //  i10 = t7^r0^t8 (q1), i11 = r0^t8 (q0)
    {
        const int g = (t ^ (t >> 1)) & 0x7F;
        float Pt = 1.0f;
#pragma unroll
        for (int m = 0; m < 7; ++m) {
            float2 cs = coI[8 - m];
            Pt *= ((g >> m) & 1) ? cs.y : cs.x;
        }
        const int ct = __popc(g);
        const int t0 = t & 1, t8 = (t >> 8) & 1;
        const int e1 = ((t >> 7) ^ (t >> 8)) & 1;
        float2 q11 = coI[11], q10 = coI[10], q9 = coI[9],
               q1 = coI[1], q0 = coI[0];
        const float u9  = t0 ? q9.y : q9.x;
        const float u9n = t0 ? q9.x : q9.y;
        const float u1  = e1 ? q1.y : q1.x;
        const float u1n = e1 ? q1.x : q1.y;
        const float u0  = t8 ? q0.y : q0.x;
        const float u0n = t8 ? q0.x : q0.y;
#pragma unroll
        for (int r = 0; r < 8; ++r) {
            const int r0 = r & 1, r1 = (r >> 1) & 1, r2 = (r >> 2) & 1;
            const int b11 = r0 ^ r1, b10 = r1 ^ r2;
            float m = Pt * (b11 ? q11.y : q11.x) * (b10 ? q10.y : q10.x)
                         * (r2 ? u9n : u9) * (r0 ? u1n : u1)
                         * (r0 ? u0n : u0);
            int k = (ct + b11 + b10 + (r2 ^ t0) + (r0 ^ e1) + (r0 ^ t8)) & 3;
            v[r].x = (k == 0) ? m : ((k == 2) ? -m : 0.0f);
            v[r].y = (k == 3) ? m : ((k == 1) ? -m : 0.0f);
        }
    }

    // ---- fused M-pass (L0 RY,RZ + L1 RX), D -> A ----
    M_PHASE(9);                       // qubits 9..11 in D
    LOCAL_X(J_D, J_C);
    M_PHASE(6);                       // qubits 6..8  in C
    LOCAL_X(J_C, J_B);
    M_PHASE(3);                       // qubits 3..5  in B
#pragma unroll
    for (int r = 0; r < 8; ++r) S[sg(J_B(r))] = v[r];  // own slice
    __syncthreads();                  // B2
#pragma unroll
    for (int r = 0; r < 8; ++r) v[r] = S[sg(J_A(r))];  // cross read
    M_PHASE(0);                       // qubits 0..2  in A

    // ---- layer-1 CNOT ring: A -> A ----
    __syncthreads();                  // B3 (all A-reads done)
#pragma unroll
    for (int r = 0; r < 8; ++r) {
        int j = J_A(r);
        int y = j ^ (j >> 1); y ^= y >> 2; y ^= y >> 4; y ^= y >> 8;
        int p = (y & 0x7FF) | (((__popc(j) ^ (j >> 11)) & 1) << 11);
        S[sg(p)] = v[r];
    }
    __syncthreads();                  // B4
#pragma unroll
    for (int r = 0; r < 8; ++r) v[r] = S[sg(J_A(r))];

    // ---- layer-1 RY (final RZ dropped: phase-only), A -> D ----
    RY_PHASE(0);                      // in A
    __syncthreads();                  // B5 (all ring-reads done)
#pragma unroll
    for (int r = 0; r < 8; ++r) S[sg(J_A(r))] = v[r];  // cross write
    __syncthreads();                  // B6
#pragma unroll
    for (int r = 0; r < 8; ++r) v[r] = S[sg(J_B(r))];  // own slice
    RY_PHASE(3);                      // in B
    LOCAL_X(J_B, J_C);
    RY_PHASE(6);                      // in C
    LOCAL_X(J_C, J_D);
    RY_PHASE(9);                      // in D

    // ---- measurement in D ----
    // qubits 9,10,11 <-> r bits 2,1,0 ; qubits 3..8 <-> lane bits 5..0 ;
    // qubits 0..2 <-> wave bits 2..0
    float ptot = 0.f, z9 = 0.f, z10 = 0.f, z11 = 0.f;
#pragma unroll
    for (int r = 0; r < 8; ++r) {
        float p = fmaf(v[r].x, v[r].x, v[r].y * v[r].y);
        ptot += p;
        z9  += (r & 4) ? -p : p;
        z10 += (r & 2) ? -p : p;
        z11 += (r & 1) ? -p : p;
    }
    // 6-stage WHT butterfly: lane L ends with sum_l (-1)^{popc(L&l)} x_l
    float vals[4] = {ptot, z9, z10, z11};
#pragma unroll
    for (int k = 0; k < 6; ++k) {
        const float sgn = ((l >> k) & 1) ? -1.f : 1.f;
#pragma unroll
        for (int m = 0; m < 4; ++m) {
            float tmp = __shfl_xor(vals[m], 1 << k, 64);
            vals[m] = fmaf(sgn, vals[m], tmp);
        }
    }
    if (l == 0) {                     // wave totals
        red[w * 12 + 0]  = vals[0];
        red[w * 12 + 9]  = vals[1];
        red[w * 12 + 10] = vals[2];
        red[w * 12 + 11] = vals[3];
    } else if (__popc(l) == 1) {      // lane-bit signed sums: qubits 3..8
        int q = 9 - __ffs(l);         // l=32 -> q=3 ... l=1 -> q=8
        red[w * 12 + q] = vals[0];
    }
    __syncthreads();                  // B7
    if (t < NQ) {
        float acc = 0.f;
#pragma unroll
        for (int ww = 0; ww < 8; ++ww) {
            float vv = red[ww * 12 + (t < 3 ? 0 : t)];
            if (t < 3) acc += ((ww >> (2 - t)) & 1) ? -vv : vv;
            else       acc += vv;
        }
        out[b * NQ + t] = acc;
    }
}

extern "C" void kernel_launch(void* const* d_in, const int* in_sizes, int n_in,
                              void* d_out, int out_size, void* d_ws, size_t ws_size,
                              hipStream_t stream) {
    const int B = in_sizes[0] / NQ;  // 1024
    vqc_kernel<<<B, TPB, 0, stream>>>((const float*)d_in[0],
                                      (const float*)d_in[1],
                                      (const float*)d_in[2],
                                      (float*)d_out);
}

// Round 10
// 78.278 us; speedup vs baseline: 1.1750x; 1.0190x over previous
//
#include <hip/hip_runtime.h>
#include <math.h>

#define NQ 12
#define TPB 256

// One 256-thread block (4 waves) per sample; 4096-amp state split 16-way:
// v[16] float2/thread = 32 VGPRs of state. The allocator hard-caps 64 VGPRs
// at TPB>=256 (R4-R6); this kernel is DESIGNED to fit: wave-uniform gate
// scalars go to SGPRs via readfirstlane, coefficients are loaded per-gate
// with tight scopes. Fewer/fatter roundtrips cut per-CU DS-pipe work ~35%
// vs R9 (5 roundtrips x 32 DS instr at 16 waves/CU vs 7 x 16 at 32).
//
// Amp index j (12 bits), qubit q <-> j bit 11-q. Register layouts
// (t = thread 0..255 gives 8 bits, r = reg index 4 bits):
//   A: j = (r<<8)|t                  r = j[11:8] = qubits 0..3
//   B: j = (t[7:4]<<8)|(r<<4)|t[3:0] r = j[7:4]  = qubits 4..7
//   C: j = (t<<4)|r                  r = j[3:0]  = qubits 8..11
// B and C share wave bits = j[11:10] -> B<->C roundtrips are wave-local
// (no barrier; same-wave LDS ordered). A<->B crossings + ring use barriers.
// LDS swizzle sg(j) = (j&~15)|((j^(j>>4)^(j>>8))&15): every leg's 16
// low-address residues are hit uniformly (bijection in the varying low
// bits) -> minimal b64 bank aliasing (family verified R7-R9, ~1.4M confl).
//
// Circuit (algebra verified R2-R9): init(C) = L0 RX product state with
// ring0 FOLDED via inverse perm; fused M_q = RX(L1)*RZ(L0)*RY(L0) in Euler
// form diag(1,e^{i psi}) RY(th) diag(1,e^{i phi}); ring1 scatter; L1 RY
// (final RZ dropped -- phase-only); <Z_q> via 6-stage WHT butterfly.

__device__ __forceinline__ int sg(int j) {
    return (j & ~15) | ((j ^ (j >> 4) ^ (j >> 8)) & 15);
}

__device__ __forceinline__ float rfl(float x) {   // force wave-uniform -> SGPR
    return __int_as_float(__builtin_amdgcn_readfirstlane(__float_as_int(x)));
}

__device__ __forceinline__ float2 pk_mul(float2 a, float2 b) {
    float2 d;
    asm("v_pk_mul_f32 %0, %1, %2" : "=v"(d) : "v"(a), "v"(b));
    return d;
}
__device__ __forceinline__ float2 pk_fma(float2 a, float2 b, float2 c) {
    float2 d;
    asm("v_pk_fma_f32 %0, %1, %2, %3" : "=v"(d) : "v"(a), "v"(b), "v"(c));
    return d;
}

#define FOR_PAIRS4(RB, STMT) do {                                     \
    const int msk_ = 1 << (RB);                                       \
    _Pragma("unroll")                                                 \
    for (int h_ = 0; h_ < 8; ++h_) {                                  \
        const int i0 = ((h_ & ~(msk_ - 1)) << 1) | (h_ & (msk_ - 1)); \
        const int i1 = i0 | msk_;                                     \
        STMT;                                                         \
    } } while (0)

#define J_A(r) (((r) << 8) | t)
#define J_B(r) (((t >> 4) << 8) | ((r) << 4) | (t & 15))
#define J_C(r) ((t << 4) | (r))

// wave-local roundtrip (same-wave LDS ordering, no barrier)
#define LOCAL_X(JS, JD) do {                                          \
    _Pragma("unroll")                                                 \
    for (int r_ = 0; r_ < 16; ++r_) S[sg(JS(r_))] = v[r_];            \
    _Pragma("unroll")                                                 \
    for (int r_ = 0; r_ < 16; ++r_) v[r_] = S[sg(JD(r_))];            \
  } while (0)

// fused M_q as diag(1,e^{i psi}) RY(th) diag(1,e^{i phi})
// mA[q] = (cth, sth, psi.x, psi.y) ; mB[q] = (phi.x, phi.y)
#define M_GATE(q, RB) do {                                                  \
        float4 A4v = mA[q]; float2 P2v = mB[q];                             \
        float az = rfl(A4v.z), aw = rfl(A4v.w);                             \
        float px = rfl(P2v.x), py = rfl(P2v.y);                             \
        float cth = rfl(A4v.x), sth = rfl(A4v.y);                           \
        float2 c2  = make_float2(cth, cth);                                 \
        float2 s2  = make_float2(sth, sth);                                 \
        float2 ms2 = make_float2(-sth, -sth);                               \
        FOR_PAIRS4(RB, {                                                    \
            float2 a1 = v[i1];                                              \
            float2 b1 = make_float2(az*a1.x - aw*a1.y,                      \
                                    az*a1.y + aw*a1.x);                     \
            float2 n0 = pk_fma(b1, ms2, pk_mul(v[i0], c2));                 \
            float2 n1 = pk_fma(v[i0], s2, pk_mul(b1, c2));                  \
            v[i0] = n0;                                                     \
            v[i1] = make_float2(px*n1.x - py*n1.y,                          \
                                px*n1.y + py*n1.x);                         \
        });                                                                 \
    } while (0)

#define RY_GATE(q, RB) do {                                                 \
        float2 csv = coY[q];                                                \
        float cth = rfl(csv.x), sth = rfl(csv.y);                           \
        float2 c2  = make_float2(cth, cth);                                 \
        float2 s2  = make_float2(sth, sth);                                 \
        float2 ms2 = make_float2(-sth, -sth);                               \
        FOR_PAIRS4(RB, {                                                    \
            float2 n0 = pk_fma(v[i1], ms2, pk_mul(v[i0], c2));              \
            float2 n1 = pk_fma(v[i0], s2, pk_mul(v[i1], c2));               \
            v[i0] = n0; v[i1] = n1;                                         \
        });                                                                 \
    } while (0)

// phase: gate qubit QB+d on r-bit 3-d (holds for A, B, C alike)
#define M_PHASE(QB)  do { _Pragma("unroll")                                 \
    for (int d_ = 0; d_ < 4; ++d_) M_GATE((QB) + d_, 3 - d_); } while (0)
#define RY_PHASE(QB) do { _Pragma("unroll")                                 \
    for (int d_ = 0; d_ < 4; ++d_) RY_GATE((QB) + d_, 3 - d_); } while (0)

__global__ __launch_bounds__(TPB) void vqc_kernel(
    const float* __restrict__ x,    // [B, 12]
    const float* __restrict__ th,   // [2, 12, 2]
    const float* __restrict__ lm,   // [2, 12]
    float* __restrict__ out)        // [B, 12]
{
    __shared__ float2 S[4096];
    __shared__ float4 mA[12];
    __shared__ float2 mB[12];
    __shared__ float2 coI[12];      // L0 RX half-angle (c,s)
    __shared__ float2 coY[12];      // L1 RY half-angle (c,s)
    __shared__ float red[4 * 12];

    const int b = blockIdx.x;
    const int t = threadIdx.x;
    const int l = t & 63;
    const int w = t >> 6;

    // ---- cooperative coefficient precompute ----
    if (t < 12) {
        float h = 0.5f * lm[t] * x[b * NQ + t];
        float c, s; __sincosf(h, &s, &c);
        coI[t] = make_float2(c, s);
    } else if (t < 24) {
        int q = t - 12;
        float h = 0.5f * th[24 + 2 * q];
        float c, s; __sincosf(h, &s, &c);
        coY[q] = make_float2(c, s);
    } else if (t < 36) {
        int q = t - 24;
        float ha = 0.5f * lm[12 + q] * x[b * NQ + q];  // L1 RX half
        float hy = 0.5f * th[2 * q];                   // L0 RY half
        float hz = 0.5f * th[2 * q + 1];               // L0 RZ half
        float ca, sa, cy, sy, cz, sz;
        __sincosf(ha, &sa, &ca);
        __sincosf(hy, &sy, &cy);
        __sincosf(hz, &sz, &cz);
        // M = RX(a) RZ(z) RY(y) in SU(2): alpha = M00, beta = M10 (R9-verified)
        float ax = ca*cy*cz + sa*sy*sz;
        float ay = -(ca*cy*sz + sa*sy*cz);
        float bx = ca*sy*cz - sa*cy*sz;
        float by = ca*sy*sz - sa*cy*cz;
        float na = ax*ax + ay*ay, nb = bx*bx + by*by;
        float ra = rsqrtf(fmaxf(na, 1e-30f));
        float rb = rsqrtf(fmaxf(nb, 1e-30f));
        float ux = ax*ra, uy = ay*ra;
        float wx = bx*rb, wy = by*rb;
        mA[q] = make_float4(na*ra, nb*rb,
                            ux*wx - uy*wy, -(ux*wy + uy*wx));
        mB[q] = make_float2(ux*wx + uy*wy, ux*wy - uy*wx);
    }
    __syncthreads();                                   // B1

    float2 v[16];

    // ---- init in layout C: L0 RX product state, ring0 folded ----
    // i = P^{-1}(j), j = (t<<4)|r:
    //  i0=r0^r1 (q11), i1=r1^r2 (q10), i2=r2^r3 (q9), i3=r3^t0 (q8),
    //  i4..i9 = gray(t) bits 0..5 (qubits 7..2),
    //  i10 = t6^r0^t7 (q1), i11 = r0^t7 (q0)
    // [hand-checked: j=1 (t=0,r=1) -> i=3073, P(3073)=1 ✓]
    {
        const int g = (t ^ (t >> 1)) & 0x3F;
        float Pt = 1.0f;
#pragma unroll
        for (int m = 0; m < 6; ++m) {
            float2 cs = coI[7 - m];
            Pt *= ((g >> m) & 1) ? cs.y : cs.x;
        }
        const int ct = __popc(g);
        const int t0 = t & 1, t7 = (t >> 7) & 1;
        const int e1 = ((t >> 6) ^ (t >> 7)) & 1;
        float2 q11 = coI[11], q10 = coI[10], q9 = coI[9],
               q8 = coI[8], q1 = coI[1], q0 = coI[0];
        const float u8  = t0 ? q8.y : q8.x;     // qubit 8, key t0^r3
        const float u8n = t0 ? q8.x : q8.y;
        const float u1  = e1 ? q1.y : q1.x;     // qubit 1, key e1^r0
        const float u1n = e1 ? q1.x : q1.y;
        const float u0  = t7 ? q0.y : q0.x;     // qubit 0, key t7^r0
        const float u0n = t7 ? q0.x : q0.y;
#pragma unroll
        for (int r = 0; r < 16; ++r) {
            const int r0 = r & 1, r1 = (r >> 1) & 1, r2 = (r >> 2) & 1,
                      r3 = (r >> 3) & 1;
            const int b11 = r0 ^ r1, b10 = r1 ^ r2, b9 = r2 ^ r3;
            float m = Pt * (b11 ? q11.y : q11.x) * (b10 ? q10.y : q10.x)
                         * (b9 ? q9.y : q9.x) * (r3 ? u8n : u8)
                         * (r0 ? u1n : u1) * (r0 ? u0n : u0);
            int k = (ct + b11 + b10 + b9 + (r3 ^ t0) + (r0 ^ e1) + (r0 ^ t7)) & 3;
            v[r].x = (k == 0) ? m : ((k == 2) ? -m : 0.0f);
            v[r].y = (k == 3) ? m : ((k == 1) ? -m : 0.0f);
        }
    }

    // ---- fused M-pass (L0 RY,RZ + L1 RX), C -> B -> A ----
    M_PHASE(8);                       // qubits 8..11 in C
    LOCAL_X(J_C, J_B);                // wave-local
    M_PHASE(4);                       // qubits 4..7  in B
#pragma unroll
    for (int r = 0; r < 16; ++r) S[sg(J_B(r))] = v[r];
    __syncthreads();                  // B2 (cross B -> A)
#pragma unroll
    for (int r = 0; r < 16; ++r) v[r] = S[sg(J_A(r))];
    M_PHASE(0);                       // qubits 0..3  in A

    // ---- layer-1 CNOT ring: A -> A ----
    __syncthreads();                  // B3 (all A-reads done)
#pragma unroll
    for (int r = 0; r < 16; ++r) {
        int j = J_A(r);
        int y = j ^ (j >> 1); y ^= y >> 2; y ^= y >> 4; y ^= y >> 8;
        int p = (y & 0x7FF) | (((__popc(j) ^ (j >> 11)) & 1) << 11);
        S[sg(p)] = v[r];
    }
    __syncthreads();                  // B4
#pragma unroll
    for (int r = 0; r < 16; ++r) v[r] = S[sg(J_A(r))];

    // ---- layer-1 RY (final RZ dropped), A -> B -> C ----
    RY_PHASE(0);                      // in A
    __syncthreads();                  // B5 (all ring-reads done)
#pragma unroll
    for (int r = 0; r < 16; ++r) S[sg(J_A(r))] = v[r];
    __syncthreads();                  // B6 (cross A -> B)
#pragma unroll
    for (int r = 0; r < 16; ++r) v[r] = S[sg(J_B(r))];
    RY_PHASE(4);                      // in B
    LOCAL_X(J_B, J_C);                // wave-local
    RY_PHASE(8);                      // in C

    // ---- measurement in C ----
    // qubits 8..11 <-> r bits 3..0 ; qubits 2..7 <-> lane bits 5..0
    // (lane bit k = j[4+k] = qubit 7-k) ; qubits 0,1 <-> wave bits 1,0
    float vals[5] = {0.f, 0.f, 0.f, 0.f, 0.f};  // ptot, z8, z9, z10, z11
#pragma unroll
    for (int r = 0; r < 16; ++r) {
        float p = fmaf(v[r].x, v[r].x, v[r].y * v[r].y);
        vals[0] += p;
        vals[1] += (r & 8) ? -p : p;
        vals[2] += (r & 4) ? -p : p;
        vals[3] += (r & 2) ? -p : p;
        vals[4] += (r & 1) ? -p : p;
    }
    // 6-stage WHT butterfly: lane L ends with sum_l (-1)^{popc(L&l)} x_l
#pragma unroll
    for (int k = 0; k < 6; ++k) {
        const float sgn = ((l >> k) & 1) ? -1.f : 1.f;
#pragma unroll
        for (int m = 0; m < 5; ++m) {
            float tmp = __shfl_xor(vals[m], 1 << k, 64);
            vals[m] = fmaf(sgn, vals[m], tmp);
        }
    }
    if (l == 0) {                     // wave totals
        red[w * 12 + 0]  = vals[0];   // ptot (for qubits 0,1)
        red[w * 12 + 8]  = vals[1];
        red[w * 12 + 9]  = vals[2];
        red[w * 12 + 10] = vals[3];
        red[w * 12 + 11] = vals[4];
    } else if (__popc(l) == 1) {      // lane-bit sums: qubits 2..7
        int q = 8 - __ffs(l);         // l=1<<k -> q = 7-k
        red[w * 12 + q] = vals[0];
    }
    __syncthreads();                  // B7
    if (t < NQ) {
        float acc = 0.f;
#pragma unroll
        for (int ww = 0; ww < 4; ++ww) {
            if (t < 2) {
                float pv = red[ww * 12 + 0];
                acc += ((ww >> (1 - t)) & 1) ? -pv : pv;
            } else {
                acc += red[ww * 12 + t];
            }
        }
        out[b * NQ + t] = acc;
    }
}

extern "C" void kernel_launch(void* const* d_in, const int* in_sizes, int n_in,
                              void* d_out, int out_size, void* d_ws, size_t ws_size,
                              hipStream_t stream) {
    const int B = in_sizes[0] / NQ;  // 1024
    vqc_kernel<<<B, TPB, 0, stream>>>((const float*)d_in[0],
                                      (const float*)d_in[1],
                                      (const float*)d_in[2],
                                      (float*)d_out);
}

// Round 11
// 74.938 us; speedup vs baseline: 1.2274x; 1.0446x over previous
//
#include <hip/hip_runtime.h>
#include <math.h>

#define NQ 12
#define TPB 256

// One 256-thread block (4 waves) per sample; 4096-amp state split 16-way:
// v[16] float2/thread = 32 VGPRs of state (fits the 64-VGPR cap the
// allocator pins at TPB>=256; R10 verified no spill).
//
// Amp index j (12 bits), qubit q <-> j bit 11-q. Register layouts
// (t = thread 0..255 gives 8 bits, r = reg index 4 bits):
//   A: j = (r<<8)|t                  r = j[11:8] = qubits 0..3
//   B: j = (t[7:4]<<8)|(r<<4)|t[3:0] r = j[7:4]  = qubits 4..7
//   C: j = (t<<4)|r                  r = j[3:0]  = qubits 8..11
// B,C share wave bits j[11:10] -> B<->C roundtrips wave-local (no barrier).
//
// R11: ALL LDS addresses strength-reduced to base ^ compile-time-const.
// sg(j) = (j&~15)|((j^(j>>4)^(j>>8))&15) and the ring map P are GF(2)-
// linear, so with kC=(t^(t>>4))&15:
//   sg(J_A(r)) = VA ^ 257r,  VA = (t&0xF0)|kC
//   sg(J_B(r)) = VB ^ 17r,   VB = ((t>>4)<<8)|kC
//   sg(J_C(r)) = VC ^ r,     VC = (t<<4)|kC
//   sg(P(j))   = Ft ^ G(r<<8), Ft per-thread, G constant-folded
// (hand-checked j=0x100, j=0x101 against the direct formulas).
// This removes ~600 address-math instrs/thread -- R9/R10 showed the kernel
// is TOTAL-ISSUE-bound, not DS-pipe-bound.
//
// Circuit (algebra verified R2-R10): init(C) = L0 RX product state with
// ring0 FOLDED via inverse perm; fused M_q = RX(L1)*RZ(L0)*RY(L0) in Euler
// form diag(1,e^{i psi}) RY(th) diag(1,e^{i phi}); ring1 scatter; L1 RY
// (final RZ dropped -- phase-only); <Z_q> via 6-stage WHT butterfly.

__device__ __forceinline__ float rfl(float x) {   // force wave-uniform -> SGPR
    return __int_as_float(__builtin_amdgcn_readfirstlane(__float_as_int(x)));
}

__device__ __forceinline__ float2 pk_mul(float2 a, float2 b) {
    float2 d;
    asm("v_pk_mul_f32 %0, %1, %2" : "=v"(d) : "v"(a), "v"(b));
    return d;
}
__device__ __forceinline__ float2 pk_fma(float2 a, float2 b, float2 c) {
    float2 d;
    asm("v_pk_fma_f32 %0, %1, %2, %3" : "=v"(d) : "v"(a), "v"(b), "v"(c));
    return d;
}

#define FOR_PAIRS4(RB, STMT) do {                                     \
    const int msk_ = 1 << (RB);                                       \
    _Pragma("unroll")                                                 \
    for (int h_ = 0; h_ < 8; ++h_) {                                  \
        const int i0 = ((h_ & ~(msk_ - 1)) << 1) | (h_ & (msk_ - 1)); \
        const int i1 = i0 | msk_;                                     \
        STMT;                                                         \
    } } while (0)

// strength-reduced swizzled addresses (VA/VB/VC/kC in scope)
#define ADDR_A(r) (VA ^ (257 * (r)))
#define ADDR_B(r) (VB ^ (17 * (r)))
#define ADDR_C(r) (VC ^ (r))

// wave-local roundtrip (same-wave LDS ordering, no barrier)
#define LOCAL_X(AS, AD) do {                                          \
    _Pragma("unroll")                                                 \
    for (int r_ = 0; r_ < 16; ++r_) S[AS(r_)] = v[r_];                \
    _Pragma("unroll")                                                 \
    for (int r_ = 0; r_ < 16; ++r_) v[r_] = S[AD(r_)];                \
  } while (0)

// fused M_q as diag(1,e^{i psi}) RY(th) diag(1,e^{i phi})
// mA[q] = (cth, sth, psi.x, psi.y) ; mB[q] = (phi.x, phi.y)
#define M_GATE(q, RB) do {                                                  \
        float4 A4v = mA[q]; float2 P2v = mB[q];                             \
        float az = rfl(A4v.z), aw = rfl(A4v.w);                             \
        float px = rfl(P2v.x), py = rfl(P2v.y);                             \
        float cth = rfl(A4v.x), sth = rfl(A4v.y);                           \
        float2 c2  = make_float2(cth, cth);                                 \
        float2 s2  = make_float2(sth, sth);                                 \
        float2 ms2 = make_float2(-sth, -sth);                               \
        FOR_PAIRS4(RB, {                                                    \
            float2 a1 = v[i1];                                              \
            float2 b1 = make_float2(az*a1.x - aw*a1.y,                      \
                                    az*a1.y + aw*a1.x);                     \
            float2 n0 = pk_fma(b1, ms2, pk_mul(v[i0], c2));                 \
            float2 n1 = pk_fma(v[i0], s2, pk_mul(b1, c2));                  \
            v[i0] = n0;                                                     \
            v[i1] = make_float2(px*n1.x - py*n1.y,                          \
                                px*n1.y + py*n1.x);                         \
        });                                                                 \
    } while (0)

#define RY_GATE(q, RB) do {                                                 \
        float2 csv = coY[q];                                                \
        float cth = rfl(csv.x), sth = rfl(csv.y);                           \
        float2 c2  = make_float2(cth, cth);                                 \
        float2 s2  = make_float2(sth, sth);                                 \
        float2 ms2 = make_float2(-sth, -sth);                               \
        FOR_PAIRS4(RB, {                                                    \
            float2 n0 = pk_fma(v[i1], ms2, pk_mul(v[i0], c2));              \
            float2 n1 = pk_fma(v[i0], s2, pk_mul(v[i1], c2));               \
            v[i0] = n0; v[i1] = n1;                                         \
        });                                                                 \
    } while (0)

// phase: gate qubit QB+d on r-bit 3-d (holds for A, B, C alike)
#define M_PHASE(QB)  do { _Pragma("unroll")                                 \
    for (int d_ = 0; d_ < 4; ++d_) M_GATE((QB) + d_, 3 - d_); } while (0)
#define RY_PHASE(QB) do { _Pragma("unroll")                                 \
    for (int d_ = 0; d_ < 4; ++d_) RY_GATE((QB) + d_, 3 - d_); } while (0)

__global__ __launch_bounds__(TPB) void vqc_kernel(
    const float* __restrict__ x,    // [B, 12]
    const float* __restrict__ th,   // [2, 12, 2]
    const float* __restrict__ lm,   // [2, 12]
    float* __restrict__ out)        // [B, 12]
{
    __shared__ float2 S[4096];
    __shared__ float4 mA[12];
    __shared__ float2 mB[12];
    __shared__ float2 coI[12];      // L0 RX half-angle (c,s)
    __shared__ float2 coY[12];      // L1 RY half-angle (c,s)
    __shared__ float red[4 * 12];

    const int b = blockIdx.x;
    const int t = threadIdx.x;
    const int l = t & 63;
    const int w = t >> 6;

    // strength-reduced address bases
    const int kC = (t ^ (t >> 4)) & 15;
    const int VA = (t & 0xF0) | kC;
    const int VB = ((t >> 4) << 8) | kC;
    const int VC = (t << 4) | kC;
    // ring per-thread part: Ft = sg(P-image of t) (GF(2)-linear split)
    int Ft;
    {
        int yt = t ^ (t >> 1); yt ^= yt >> 2; yt ^= yt >> 4; yt ^= yt >> 8;
        int pt = (yt & 0x7FF) | ((__popc(t) & 1) << 11);
        Ft = (pt & ~15) | ((pt ^ (pt >> 4) ^ (pt >> 8)) & 15);
    }

    // ---- cooperative coefficient precompute ----
    if (t < 12) {
        float h = 0.5f * lm[t] * x[b * NQ + t];
        float c, s; __sincosf(h, &s, &c);
        coI[t] = make_float2(c, s);
    } else if (t < 24) {
        int q = t - 12;
        float h = 0.5f * th[24 + 2 * q];
        float c, s; __sincosf(h, &s, &c);
        coY[q] = make_float2(c, s);
    } else if (t < 36) {
        int q = t - 24;
        float ha = 0.5f * lm[12 + q] * x[b * NQ + q];  // L1 RX half
        float hy = 0.5f * th[2 * q];                   // L0 RY half
        float hz = 0.5f * th[2 * q + 1];               // L0 RZ half
        float ca, sa, cy, sy, cz, sz;
        __sincosf(ha, &sa, &ca);
        __sincosf(hy, &sy, &cy);
        __sincosf(hz, &sz, &cz);
        // M = RX(a) RZ(z) RY(y) in SU(2): alpha = M00, beta = M10 (R9-verified)
        float ax = ca*cy*cz + sa*sy*sz;
        float ay = -(ca*cy*sz + sa*sy*cz);
        float bx = ca*sy*cz - sa*cy*sz;
        float by = ca*sy*sz - sa*cy*cz;
        float na = ax*ax + ay*ay, nb = bx*bx + by*by;
        float ra = rsqrtf(fmaxf(na, 1e-30f));
        float rb = rsqrtf(fmaxf(nb, 1e-30f));
        float ux = ax*ra, uy = ay*ra;
        float wx = bx*rb, wy = by*rb;
        mA[q] = make_float4(na*ra, nb*rb,
                            ux*wx - uy*wy, -(ux*wy + uy*wx));
        mB[q] = make_float2(ux*wx + uy*wy, ux*wy - uy*wx);
    }
    __syncthreads();                                   // B1

    float2 v[16];

    // ---- init in layout C: L0 RX product state, ring0 folded ----
    // (R10-verified) i = P^{-1}(j), j = (t<<4)|r:
    //  i0=r0^r1 (q11), i1=r1^r2 (q10), i2=r2^r3 (q9), i3=r3^t0 (q8),
    //  i4..i9 = gray(t) bits 0..5 (qubits 7..2),
    //  i10 = t6^r0^t7 (q1), i11 = r0^t7 (q0)
    {
        const int g = (t ^ (t >> 1)) & 0x3F;
        float Pt = 1.0f;
#pragma unroll
        for (int m = 0; m < 6; ++m) {
            float2 cs = coI[7 - m];
            Pt *= ((g >> m) & 1) ? cs.y : cs.x;
        }
        const int ct = __popc(g);
        const int t0 = t & 1, t7 = (t >> 7) & 1;
        const int e1 = ((t >> 6) ^ (t >> 7)) & 1;
        float2 q11 = coI[11], q10 = coI[10], q9 = coI[9],
               q8 = coI[8], q1 = coI[1], q0 = coI[0];
        const float u8  = t0 ? q8.y : q8.x;     // qubit 8, key t0^r3
        const float u8n = t0 ? q8.x : q8.y;
        const float u1  = e1 ? q1.y : q1.x;     // qubit 1, key e1^r0
        const float u1n = e1 ? q1.x : q1.y;
        const float u0  = t7 ? q0.y : q0.x;     // qubit 0, key t7^r0
        const float u0n = t7 ? q0.x : q0.y;
#pragma unroll
        for (int r = 0; r < 16; ++r) {
            const int r0 = r & 1, r1 = (r >> 1) & 1, r2 = (r >> 2) & 1,
                      r3 = (r >> 3) & 1;
            const int b11 = r0 ^ r1, b10 = r1 ^ r2, b9 = r2 ^ r3;
            float m = Pt * (b11 ? q11.y : q11.x) * (b10 ? q10.y : q10.x)
                         * (b9 ? q9.y : q9.x) * (r3 ? u8n : u8)
                         * (r0 ? u1n : u1) * (r0 ? u0n : u0);
            int k = (ct + b11 + b10 + b9 + (r3 ^ t0) + (r0 ^ e1) + (r0 ^ t7)) & 3;
            v[r].x = (k == 0) ? m : ((k == 2) ? -m : 0.0f);
            v[r].y = (k == 3) ? m : ((k == 1) ? -m : 0.0f);
        }
    }

    // ---- fused M-pass (L0 RY,RZ + L1 RX), C -> B -> A ----
    M_PHASE(8);                       // qubits 8..11 in C
    LOCAL_X(ADDR_C, ADDR_B);          // wave-local
    M_PHASE(4);                       // qubits 4..7  in B
#pragma unroll
    for (int r = 0; r < 16; ++r) S[ADDR_B(r)] = v[r];
    __syncthreads();                  // B2 (cross B -> A)
#pragma unroll
    for (int r = 0; r < 16; ++r) v[r] = S[ADDR_A(r)];
    M_PHASE(0);                       // qubits 0..3  in A

    // ---- layer-1 CNOT ring: A -> A (addr = Ft ^ const-folded G(r<<8)) ----
    __syncthreads();                  // B3 (all A-reads done)
#pragma unroll
    for (int r = 0; r < 16; ++r) {
        const int jr = r << 8;
        int yr = jr ^ (jr >> 1); yr ^= yr >> 2; yr ^= yr >> 4; yr ^= yr >> 8;
        const int pr = (yr & 0x7FF) | (((__popc(jr) ^ (jr >> 11)) & 1) << 11);
        const int Gr = (pr & ~15) | ((pr ^ (pr >> 4) ^ (pr >> 8)) & 15);
        S[Ft ^ Gr] = v[r];
    }
    __syncthreads();                  // B4
#pragma unroll
    for (int r = 0; r < 16; ++r) v[r] = S[ADDR_A(r)];

    // ---- layer-1 RY (final RZ dropped), A -> B -> C ----
    RY_PHASE(0);                      // in A
    __syncthreads();                  // B5 (all ring-reads done)
#pragma unroll
    for (int r = 0; r < 16; ++r) S[ADDR_A(r)] = v[r];
    __syncthreads();                  // B6 (cross A -> B)
#pragma unroll
    for (int r = 0; r < 16; ++r) v[r] = S[ADDR_B(r)];
    RY_PHASE(4);                      // in B
    LOCAL_X(ADDR_B, ADDR_C);          // wave-local
    RY_PHASE(8);                      // in C

    // ---- measurement in C ----
    // qubits 8..11 <-> r bits 3..0 ; qubits 2..7 <-> lane bits 5..0
    // (lane bit k = j[4+k] = qubit 7-k) ; qubits 0,1 <-> wave bits 1,0
    float vals[5] = {0.f, 0.f, 0.f, 0.f, 0.f};  // ptot, z8, z9, z10, z11
#pragma unroll
    for (int r = 0; r < 16; ++r) {
        float p = fmaf(v[r].x, v[r].x, v[r].y * v[r].y);
        vals[0] += p;
        vals[1] += (r & 8) ? -p : p;
        vals[2] += (r & 4) ? -p : p;
        vals[3] += (r & 2) ? -p : p;
        vals[4] += (r & 1) ? -p : p;
    }
    // 6-stage WHT butterfly: lane L ends with sum_l (-1)^{popc(L&l)} x_l
#pragma unroll
    for (int k = 0; k < 6; ++k) {
        const float sgn = ((l >> k) & 1) ? -1.f : 1.f;
#pragma unroll
        for (int m = 0; m < 5; ++m) {
            float tmp = __shfl_xor(vals[m], 1 << k, 64);
            vals[m] = fmaf(sgn, vals[m], tmp);
        }
    }
    if (l == 0) {                     // wave totals
        red[w * 12 + 0]  = vals[0];   // ptot (for qubits 0,1)
        red[w * 12 + 8]  = vals[1];
        red[w * 12 + 9]  = vals[2];
        red[w * 12 + 10] = vals[3];
        red[w * 12 + 11] = vals[4];
    } else if (__popc(l) == 1) {      // lane-bit sums: qubits 2..7
        int q = 8 - __ffs(l);         // l=1<<k -> q = 7-k
        red[w * 12 + q] = vals[0];
    }
    __syncthreads();                  // B7
    if (t < NQ) {
        float acc = 0.f;
#pragma unroll
        for (int ww = 0; ww < 4; ++ww) {
            if (t < 2) {
                float pv = red[ww * 12 + 0];
                acc += ((ww >> (1 - t)) & 1) ? -pv : pv;
            } else {
                acc += red[ww * 12 + t];
            }
        }
        out[b * NQ + t] = acc;
    }
}

extern "C" void kernel_launch(void* const* d_in, const int* in_sizes, int n_in,
                              void* d_out, int out_size, void* d_ws, size_t ws_size,
                              hipStream_t stream) {
    const int B = in_sizes[0] / NQ;  // 1024
    vqc_kernel<<<B, TPB, 0, stream>>>((const float*)d_in[0],
                                      (const float*)d_in[1],
                                      (const float*)d_in[2],
                                      (float*)d_out);
}